// Round 2
// baseline (1551.044 us; speedup 1.0000x reference)
//
#include <hip/hip_runtime.h>

// FFT-based causal long convolution for (b=4, l=8192, d=1024) fp32.
// Single kernel, one workgroup per d; inner loop over b. Real FFT of N=16384
// as complex FFT of M=8192 via even/odd packing; 64 KB LDS.
//
// vs previous version:
//  - Radix-2^5 / 2^5 / 2^3 fused passes: 32-point (or 4x8-point) groups held
//    in registers; 13 radix-2 stages in 3 LDS round-trips per FFT (was 7).
//    One sincos + 4 complex squarings per pass gives all stage twiddles;
//    intra-group roots are compile-time constants (CR table).
//  - First forward pass loads x/filt directly global->registers (mapping
//    m = tid + 256 t IS the hs=256 group); last inverse pass stores y directly
//    from registers. 6 LDS round-trips per pipeline total (was 14).
//  - Unified kernel: grid=1024 blocks (one per d, exactly 2 occupancy rounds),
//    filter spectrum K kept in 68 VGPRs across the b-loop. No workspace, no
//    second dispatch, no K_f HBM traffic.
//  - Same swz() LDS swizzle, same rev13 unpack / phase C (stage order of the
//    fused ladder is identical to the verified radix-2 version).

#define M 8192
#define NTH 256
#define MAXP 17           // ceil((M/2+1)/NTH)

__device__ __forceinline__ float2 cadd(float2 a, float2 b){ return make_float2(a.x+b.x, a.y+b.y); }
__device__ __forceinline__ float2 csub(float2 a, float2 b){ return make_float2(a.x-b.x, a.y-b.y); }
__device__ __forceinline__ float2 cmul(float2 a, float2 b){ return make_float2(a.x*b.x - a.y*b.y, a.x*b.y + a.y*b.x); }
__device__ __forceinline__ float2 conjf2(float2 a){ return make_float2(a.x, -a.y); }
__device__ __forceinline__ int rev13(int k){ return (int)(__brev((unsigned)k) >> 19); }
__device__ __forceinline__ int swz(int e){ return e ^ ((e >> 4) & 15) ^ ((e >> 8) & 15); }

static __device__ const float PI_F = 3.14159265358979323846f;

// cos/sin(pi*u/16); indexed with compile-time u in fully unrolled loops.
constexpr float CR_C[17] = {
  1.f, 0.98078528f, 0.92387953f, 0.83146961f, 0.70710678f,
  0.55557023f, 0.38268343f, 0.19509032f, 0.f, -0.19509032f,
  -0.38268343f, -0.55557023f, -0.70710678f, -0.83146961f,
  -0.92387953f, -0.98078528f, -1.f };
constexpr float CR_S[17] = {
  0.f, 0.19509032f, 0.38268343f, 0.55557023f, 0.70710678f,
  0.83146961f, 0.92387953f, 0.98078528f, 1.f, 0.98078528f,
  0.92387953f, 0.83146961f, 0.70710678f, 0.55557023f,
  0.38268343f, 0.19509032f, 0.f };

// a * e^{-i*pi*idx/16} (fwd) or a * e^{+i*pi*idx/16} (inv); idx compile-time.
__device__ __forceinline__ float2 cmul_cr(float2 a, int idx, bool inv) {
  if (idx == 0) return a;
  const float c = CR_C[idx], s = CR_S[idx];
  if (!inv) return make_float2(a.x*c + a.y*s, a.y*c - a.x*s);
  return make_float2(a.x*c - a.y*s, a.x*s + a.y*c);
}

// 5 fused radix-2 stages on a 32-point register group.
// Group = global indices { base + t*HS : t=0..31 }, r = base mod HS.
// Forward (DIF): halves 16HS..HS ; stage st has D=16>>st, base twiddle
//   e^{-i*pi*r/(HS*D)} = w0^(2^st), w0 = e^{-i*pi*r/(16 HS)}; intra-group root
//   e^{-i*pi*u/D}. Inverse (DIT): halves HS..16HS, conjugate signs, base
//   twiddle exponent 16/D -> w0^(2^(4-st)).
// FIRST_PAD: forward only, p[16..31] known zero (zero-padded input).
// LAST_HALF: inverse only, final-stage upper outputs not needed.
template<int HS, bool INV, bool FIRST_PAD, bool LAST_HALF>
__device__ __forceinline__ void fft5_regs(float2 (&p)[32], int r) {
  float s, c;
  const float th = PI_F * (float)r * (1.0f / (16.0f * (float)HS));
  __sincosf(INV ? th : -th, &s, &c);
  float2 w[5];
  w[0] = make_float2(c, s);
  w[1] = cmul(w[0], w[0]);
  w[2] = cmul(w[1], w[1]);
  w[3] = cmul(w[2], w[2]);
  w[4] = cmul(w[3], w[3]);
  if (!INV) {
#pragma unroll
    for (int st = 0; st < 5; ++st) {
      const int D = 16 >> st;
#pragma unroll
      for (int t0 = 0; t0 < 32; ++t0) {
        if ((t0 & D) == 0) {
          const int u = t0 & (D - 1);
          float2 a = p[t0];
          if (FIRST_PAD && st == 0) {
            // b == 0: sum = a, diff = a.
            p[t0 + D] = cmul_cr(cmul(a, w[0]), u, false);   // idx = u*(16/16)
          } else {
            float2 b = p[t0 + D];
            p[t0] = cadd(a, b);
            p[t0 + D] = cmul_cr(cmul(csub(a, b), w[st]), u * (16 / D), false);
          }
        }
      }
    }
  } else {
#pragma unroll
    for (int st = 0; st < 5; ++st) {
      const int D = 1 << st;
#pragma unroll
      for (int t0 = 0; t0 < 32; ++t0) {
        if ((t0 & D) == 0) {
          const int u = t0 & (D - 1);
          float2 b = cmul_cr(cmul(p[t0 + D], w[4 - st]), u * (16 / D), true);
          float2 a = p[t0];
          p[t0] = cadd(a, b);
          if (!(LAST_HALF && st == 4)) p[t0 + D] = csub(a, b);
        }
      }
    }
  }
}

// Middle fused-5 pass, LDS -> registers -> LDS.
template<int HS, bool INV>
__device__ __forceinline__ void pass5_lds(float2* L, int tid) {
  const int r = tid & (HS - 1);
  const int base = ((tid - r) << 5) + r;     // (tid/HS)*32*HS + r
  float2 p[32];
#pragma unroll
  for (int t = 0; t < 32; ++t) p[t] = L[swz(base + t * HS)];
  fft5_regs<HS, INV, false, false>(p, r);
#pragma unroll
  for (int t = 0; t < 32; ++t) L[swz(base + t * HS)] = p[t];
}

// 3 fused stages (halves 4,2,1), hs=1: 4 groups of 8 consecutive points per
// thread, r=0 => no sincos, constant roots only.
template<bool INV>
__device__ __forceinline__ void pass3_lds(float2* L, int tid) {
#pragma unroll
  for (int g = 0; g < 4; ++g) {
    const int base = tid * 32 + g * 8;
    float2 p[8];
#pragma unroll
    for (int t = 0; t < 8; ++t) p[t] = L[swz(base + t)];
    if (!INV) {
#pragma unroll
      for (int st = 0; st < 3; ++st) {
        const int D = 4 >> st;
#pragma unroll
        for (int t0 = 0; t0 < 8; ++t0) {
          if ((t0 & D) == 0) {
            const int u = t0 & (D - 1);
            float2 a = p[t0], b = p[t0 + D];
            p[t0] = cadd(a, b);
            p[t0 + D] = cmul_cr(csub(a, b), u * (16 / D), false);
          }
        }
      }
    } else {
#pragma unroll
      for (int st = 0; st < 3; ++st) {
        const int D = 1 << st;
#pragma unroll
        for (int t0 = 0; t0 < 8; ++t0) {
          if ((t0 & D) == 0) {
            const int u = t0 & (D - 1);
            float2 b = cmul_cr(p[t0 + D], u * (16 / D), true);
            float2 a = p[t0];
            p[t0] = cadd(a, b);
            p[t0 + D] = csub(a, b);
          }
        }
      }
    }
#pragma unroll
    for (int t = 0; t < 8; ++t) L[swz(base + t)] = p[t];
  }
}

__global__ __launch_bounds__(NTH, 2)
void longconv_fft_kernel(const float* __restrict__ x,
                         const float* __restrict__ filt,
                         float* __restrict__ y,
                         int B) {
  __shared__ float2 L[M];                    // 64 KB
  const int tid = threadIdx.x;

  // Bijective XCD-aware swizzle: XCD j owns a contiguous chunk of d values.
  const int nwg = gridDim.x;                 // 1024, multiple of 8
  const int cpx = nwg >> 3;
  const int bid = blockIdx.x;
  const int d   = (bid & 7) * cpx + (bid >> 3);

  float2 Kk[MAXP], Kmk[MAXP];

  // ---------------- Phase A: filter FFT -> K in registers ----------------
  {
    const float* fp = filt + (size_t)d * 8192;
    float2 p[32];
#pragma unroll
    for (int t = 0; t < 16; ++t) {
      int m = tid + t * NTH;                 // 0..4095
      p[t] = make_float2(fp[2*m], fp[2*m + 1]);
    }
#pragma unroll
    for (int t = 16; t < 32; ++t) p[t] = make_float2(0.f, 0.f);
    fft5_regs<256, false, true, false>(p, tid);   // halves 4096..256
#pragma unroll
    for (int t = 0; t < 32; ++t) L[swz(tid + t * 256)] = p[t];
    __syncthreads();
    pass5_lds<8, false>(L, tid);             // halves 128..8
    __syncthreads();
    pass3_lds<false>(L, tid);                // halves 4,2,1
    __syncthreads();
#pragma unroll
    for (int pq = 0; pq < MAXP; ++pq) {
      int k = tid + pq * NTH;
      if (k <= M/2) {
        int rk  = rev13(k);
        int rmk = rev13((M - k) & (M - 1));
        float2 Zk = L[swz(rk)], Zmk = L[swz(rmk)];
        float2 Ze = make_float2(0.5f*(Zk.x + Zmk.x), 0.5f*(Zk.y - Zmk.y));
        float2 t  = make_float2(Zk.x - Zmk.x, Zk.y + Zmk.y);
        float2 Zo = make_float2(0.5f*t.y, -0.5f*t.x);
        float s, c; __sincosf(-PI_F * (float)k * (1.0f/(float)M), &s, &c);
        float2 W = make_float2(c, s);
        float2 WZo = cmul(W, Zo);
        Kk[pq]  = cadd(Ze, WZo);             // K[k]
        Kmk[pq] = conjf2(csub(Ze, WZo));     // K[M-k]
      }
    }
    __syncthreads();                         // all reads of L done before reuse
  }

  // ---------------- Per-batch pipeline ----------------
  for (int b = 0; b < B; ++b) {
    // Phase B: load x directly into the hs=256 register group, forward pass 1.
    {
      const float* xp = x + (size_t)b * (8192 * 1024) + d;
      float2 p[32];
#pragma unroll
      for (int t = 0; t < 16; ++t) {
        int m = tid + t * NTH;
        p[t] = make_float2(xp[(size_t)(2*m)     * 1024],
                           xp[(size_t)(2*m + 1) * 1024]);
      }
#pragma unroll
      for (int t = 16; t < 32; ++t) p[t] = make_float2(0.f, 0.f);
      fft5_regs<256, false, true, false>(p, tid);
#pragma unroll
      for (int t = 0; t < 32; ++t) L[swz(tid + t * 256)] = p[t];
    }
    __syncthreads();
    pass5_lds<8, false>(L, tid);
    __syncthreads();
    pass3_lds<false>(L, tid);
    __syncthreads();

    // Phase C: unpack * K, repack (in place, pairwise).
#pragma unroll
    for (int pq = 0; pq < MAXP; ++pq) {
      int k = tid + pq * NTH;
      if (k <= M/2) {
        int rk  = rev13(k);
        int rmk = rev13((M - k) & (M - 1));
        float2 Zk = L[swz(rk)], Zmk = L[swz(rmk)];
        float2 Ze = make_float2(0.5f*(Zk.x + Zmk.x), 0.5f*(Zk.y - Zmk.y));
        float2 t  = make_float2(Zk.x - Zmk.x, Zk.y + Zmk.y);
        float2 Zo = make_float2(0.5f*t.y, -0.5f*t.x);
        float s, c; __sincosf(-PI_F * (float)k * (1.0f/(float)M), &s, &c);
        float2 W = make_float2(c, s);
        float2 WZo = cmul(W, Zo);
        float2 Uk  = cadd(Ze, WZo);
        float2 Umk = conjf2(csub(Ze, WZo));
        float2 Yk  = cmul(Uk,  Kk[pq]);
        float2 Ymk = cmul(Umk, Kmk[pq]);
        float2 Ye  = make_float2(0.5f*(Yk.x + Ymk.x), 0.5f*(Yk.y - Ymk.y));
        float2 t2  = make_float2(0.5f*(Yk.x - Ymk.x), 0.5f*(Yk.y + Ymk.y));
        float2 Zoy = cmul(conjf2(W), t2);
        float2 Zyk  = make_float2(Ye.x - Zoy.y, Ye.y + Zoy.x);
        float2 Zymk = make_float2(Ye.x + Zoy.y, Zoy.x - Ye.y);
        L[swz(rk)]  = Zyk;
        L[swz(rmk)] = Zymk;                  // k==0 / k==M/2: same slot, same value
      }
    }
    __syncthreads();

    // Phase D: inverse FFT.
    pass3_lds<true>(L, tid);                 // halves 1,2,4
    __syncthreads();
    pass5_lds<8, true>(L, tid);              // halves 8..128
    __syncthreads();

    // Final inverse pass (halves 256..4096) + direct register store of y.
    {
      float2 p[32];
#pragma unroll
      for (int t = 0; t < 32; ++t) p[t] = L[swz(tid + t * 256)];
      fft5_regs<256, true, false, true>(p, tid);
      float* yp = y + (size_t)b * (8192 * 1024) + d;
      const float inv = 1.0f / (float)M;
#pragma unroll
      for (int t = 0; t < 16; ++t) {
        int m = tid + t * NTH;               // 0..4095 = first l samples (packed)
        yp[(size_t)(2*m)     * 1024] = p[t].x * inv;
        yp[(size_t)(2*m + 1) * 1024] = p[t].y * inv;
      }
    }
    __syncthreads();                         // L reads done before next b's writes
  }
}

extern "C" void kernel_launch(void* const* d_in, const int* in_sizes, int n_in,
                              void* d_out, int out_size, void* d_ws, size_t ws_size,
                              hipStream_t stream) {
  const float* x    = (const float*)d_in[0];   // (b, l, d) fp32
  const float* filt = (const float*)d_in[1];   // (d, l) fp32
  float* y = (float*)d_out;                    // (b, l, d) fp32

  const int D = 1024, Lseq = 8192;
  const int B = in_sizes[0] / (D * Lseq);      // 4

  dim3 grid(D), block(NTH);
  hipLaunchKernelGGL(longconv_fft_kernel, grid, block, 0, stream, x, filt, y, B);
}

// Round 3
// 840.599 us; speedup vs baseline: 1.8452x; 1.8452x over previous
//
#include <hip/hip_runtime.h>

// FFT-based causal long convolution for (b=4, l=8192, d=1024) fp32.
// One workgroup per (b, d) pair. Real FFT of N=16384 as complex FFT of M=8192
// via even/odd packing; 64 KB LDS holds the whole sequence.
//
// Structure = round-1 memory layout + round-2 fused passes:
//  - Radix-2^5 / 2^5 / 2^3 fused passes: 13 radix-2 stages in 3 LDS
//    round-trips per FFT. One sincos + 4 complex squarings per pass gives all
//    stage twiddles; intra-group roots are compile-time constants.
//  - First forward pass loads x directly global->registers; last inverse pass
//    stores y directly from registers.
//  - Filter spectrum precomputed once per d into workspace (float4 = K[k],
//    K[M-k]) by filt_fft_kernel; main kernel reads it as short-lived float4
//    loads in phase C. NO persistent K registers across the pipeline (the
//    round-2 regression: K[17]+p[32] live sets -> scratch spill -> 3 GB of
//    HBM scratch traffic). Peak live set here is p[32]+twiddles (~110 VGPR).
//  - 4096 blocks, bijective XCD swizzle: each XCD owns one b x 512
//    consecutive d -> strided 4B/4KB x-reads and y-writes merge into full
//    lines in its private L2 (round-1 proven: WRITE ~= ideal).

#define M 8192
#define NTH 256
#define MAXP 17           // ceil((M/2+1)/NTH)

__device__ __forceinline__ float2 cadd(float2 a, float2 b){ return make_float2(a.x+b.x, a.y+b.y); }
__device__ __forceinline__ float2 csub(float2 a, float2 b){ return make_float2(a.x-b.x, a.y-b.y); }
__device__ __forceinline__ float2 cmul(float2 a, float2 b){ return make_float2(a.x*b.x - a.y*b.y, a.x*b.y + a.y*b.x); }
__device__ __forceinline__ float2 conjf2(float2 a){ return make_float2(a.x, -a.y); }
__device__ __forceinline__ int rev13(int k){ return (int)(__brev((unsigned)k) >> 19); }
__device__ __forceinline__ int swz(int e){ return e ^ ((e >> 4) & 15) ^ ((e >> 8) & 15); }

static __device__ const float PI_F = 3.14159265358979323846f;

// cos/sin(pi*u/16); indexed with compile-time u in fully unrolled loops.
constexpr float CR_C[17] = {
  1.f, 0.98078528f, 0.92387953f, 0.83146961f, 0.70710678f,
  0.55557023f, 0.38268343f, 0.19509032f, 0.f, -0.19509032f,
  -0.38268343f, -0.55557023f, -0.70710678f, -0.83146961f,
  -0.92387953f, -0.98078528f, -1.f };
constexpr float CR_S[17] = {
  0.f, 0.19509032f, 0.38268343f, 0.55557023f, 0.70710678f,
  0.83146961f, 0.92387953f, 0.98078528f, 1.f, 0.98078528f,
  0.92387953f, 0.83146961f, 0.70710678f, 0.55557023f,
  0.38268343f, 0.19509032f, 0.f };

// a * e^{-i*pi*idx/16} (fwd) or a * e^{+i*pi*idx/16} (inv); idx compile-time.
__device__ __forceinline__ float2 cmul_cr(float2 a, int idx, bool inv) {
  if (idx == 0) return a;
  const float c = CR_C[idx], s = CR_S[idx];
  if (!inv) return make_float2(a.x*c + a.y*s, a.y*c - a.x*s);
  return make_float2(a.x*c - a.y*s, a.x*s + a.y*c);
}

// 5 fused radix-2 stages on a 32-point register group.
// Group = global indices { base + t*HS : t=0..31 }, r = base mod HS.
// Forward (DIF): halves 16HS..HS. Inverse (DIT): halves HS..16HS.
// FIRST_PAD: forward only, p[16..31] known zero (zero-padded input).
// LAST_HALF: inverse only, final-stage upper outputs not needed.
template<int HS, bool INV, bool FIRST_PAD, bool LAST_HALF>
__device__ __forceinline__ void fft5_regs(float2 (&p)[32], int r) {
  float s, c;
  const float th = PI_F * (float)r * (1.0f / (16.0f * (float)HS));
  __sincosf(INV ? th : -th, &s, &c);
  float2 w[5];
  w[0] = make_float2(c, s);
  w[1] = cmul(w[0], w[0]);
  w[2] = cmul(w[1], w[1]);
  w[3] = cmul(w[2], w[2]);
  w[4] = cmul(w[3], w[3]);
  if (!INV) {
#pragma unroll
    for (int st = 0; st < 5; ++st) {
      const int D = 16 >> st;
#pragma unroll
      for (int t0 = 0; t0 < 32; ++t0) {
        if ((t0 & D) == 0) {
          const int u = t0 & (D - 1);
          float2 a = p[t0];
          if (FIRST_PAD && st == 0) {
            // b == 0: sum = a, diff = a.
            p[t0 + D] = cmul_cr(cmul(a, w[0]), u, false);
          } else {
            float2 b = p[t0 + D];
            p[t0] = cadd(a, b);
            p[t0 + D] = cmul_cr(cmul(csub(a, b), w[st]), u * (16 / D), false);
          }
        }
      }
    }
  } else {
#pragma unroll
    for (int st = 0; st < 5; ++st) {
      const int D = 1 << st;
#pragma unroll
      for (int t0 = 0; t0 < 32; ++t0) {
        if ((t0 & D) == 0) {
          const int u = t0 & (D - 1);
          float2 b = cmul_cr(cmul(p[t0 + D], w[4 - st]), u * (16 / D), true);
          float2 a = p[t0];
          p[t0] = cadd(a, b);
          if (!(LAST_HALF && st == 4)) p[t0 + D] = csub(a, b);
        }
      }
    }
  }
}

// Middle fused-5 pass, LDS -> registers -> LDS.
template<int HS, bool INV>
__device__ __forceinline__ void pass5_lds(float2* L, int tid) {
  const int r = tid & (HS - 1);
  const int base = ((tid - r) << 5) + r;     // (tid/HS)*32*HS + r
  float2 p[32];
#pragma unroll
  for (int t = 0; t < 32; ++t) p[t] = L[swz(base + t * HS)];
  fft5_regs<HS, INV, false, false>(p, r);
#pragma unroll
  for (int t = 0; t < 32; ++t) L[swz(base + t * HS)] = p[t];
}

// 3 fused stages (halves 4,2,1), hs=1: 4 groups of 8 consecutive points per
// thread, r=0 => no sincos, constant roots only.
template<bool INV>
__device__ __forceinline__ void pass3_lds(float2* L, int tid) {
#pragma unroll
  for (int g = 0; g < 4; ++g) {
    const int base = tid * 32 + g * 8;
    float2 p[8];
#pragma unroll
    for (int t = 0; t < 8; ++t) p[t] = L[swz(base + t)];
    if (!INV) {
#pragma unroll
      for (int st = 0; st < 3; ++st) {
        const int D = 4 >> st;
#pragma unroll
        for (int t0 = 0; t0 < 8; ++t0) {
          if ((t0 & D) == 0) {
            const int u = t0 & (D - 1);
            float2 a = p[t0], b = p[t0 + D];
            p[t0] = cadd(a, b);
            p[t0 + D] = cmul_cr(csub(a, b), u * (16 / D), false);
          }
        }
      }
    } else {
#pragma unroll
      for (int st = 0; st < 3; ++st) {
        const int D = 1 << st;
#pragma unroll
        for (int t0 = 0; t0 < 8; ++t0) {
          if ((t0 & D) == 0) {
            const int u = t0 & (D - 1);
            float2 b = cmul_cr(p[t0 + D], u * (16 / D), true);
            float2 a = p[t0];
            p[t0] = cadd(a, b);
            p[t0 + D] = csub(a, b);
          }
        }
      }
    }
#pragma unroll
    for (int t = 0; t < 8; ++t) L[swz(base + t)] = p[t];
  }
}

// Precompute per-d filter spectrum: (K[k], K[M-k]) for k=0..M/2 as float4.
__global__ __launch_bounds__(NTH, 2)
void filt_fft_kernel(const float* __restrict__ filt, float4* __restrict__ kf) {
  __shared__ float2 L[M];
  const int tid = threadIdx.x;
  const int d = blockIdx.x;
  const float* fp = filt + (size_t)d * 8192;
  {
    float2 p[32];
#pragma unroll
    for (int t = 0; t < 16; ++t) {
      int m = tid + t * NTH;
      p[t] = make_float2(fp[2*m], fp[2*m + 1]);
    }
#pragma unroll
    for (int t = 16; t < 32; ++t) p[t] = make_float2(0.f, 0.f);
    fft5_regs<256, false, true, false>(p, tid);      // halves 4096..256
#pragma unroll
    for (int t = 0; t < 32; ++t) L[swz(tid + t * 256)] = p[t];
  }
  __syncthreads();
  pass5_lds<8, false>(L, tid);                       // halves 128..8
  __syncthreads();
  pass3_lds<false>(L, tid);                          // halves 4,2,1
  __syncthreads();
  float4* out = kf + (size_t)d * (M/2 + 1);
  for (int k = tid; k <= M/2; k += NTH) {
    int rk  = rev13(k);
    int rmk = rev13((M - k) & (M - 1));
    float2 Zk = L[swz(rk)], Zmk = L[swz(rmk)];
    float2 Ze = make_float2(0.5f*(Zk.x + Zmk.x), 0.5f*(Zk.y - Zmk.y));
    float2 t  = make_float2(Zk.x - Zmk.x, Zk.y + Zmk.y);
    float2 Zo = make_float2(0.5f*t.y, -0.5f*t.x);
    float s, c; __sincosf(-PI_F * (float)k * (1.0f/(float)M), &s, &c);
    float2 W = make_float2(c, s);
    float2 WZo = cmul(W, Zo);
    float2 Kk = cadd(Ze, WZo);
    float2 Km = conjf2(csub(Ze, WZo));
    out[k] = make_float4(Kk.x, Kk.y, Km.x, Km.y);
  }
}

__global__ __launch_bounds__(NTH, 2)
void longconv_fft_kernel(const float* __restrict__ x,
                         const float* __restrict__ filt,
                         const float4* __restrict__ kf,   // may be null
                         float* __restrict__ y,
                         int B) {
  __shared__ float2 L[M];                    // 64 KB
  const int tid = threadIdx.x;

  // Bijective XCD swizzle: XCD j owns 512 consecutive blk = one b, 512
  // consecutive d -> co-resident blocks share x/y cache lines in its L2.
  const int nwg = gridDim.x;                 // 4096, multiple of 8
  const int cpx = nwg >> 3;
  const int bid = blockIdx.x;
  const int blk = (bid & 7) * cpx + (bid >> 3);
  const int d = blk & 1023;
  const int b = blk >> 10;

  float2 Kk[MAXP], Kmk[MAXP];               // FALLBACK ONLY (kf==nullptr)

  // ---------------- Phase A: filter FFT (fallback only) ----------------
  if (kf == nullptr) {
    const float* fp = filt + (size_t)d * 8192;
    {
      float2 p[32];
#pragma unroll
      for (int t = 0; t < 16; ++t) {
        int m = tid + t * NTH;
        p[t] = make_float2(fp[2*m], fp[2*m + 1]);
      }
#pragma unroll
      for (int t = 16; t < 32; ++t) p[t] = make_float2(0.f, 0.f);
      fft5_regs<256, false, true, false>(p, tid);
#pragma unroll
      for (int t = 0; t < 32; ++t) L[swz(tid + t * 256)] = p[t];
    }
    __syncthreads();
    pass5_lds<8, false>(L, tid);
    __syncthreads();
    pass3_lds<false>(L, tid);
    __syncthreads();
#pragma unroll
    for (int pq = 0; pq < MAXP; ++pq) {
      int k = tid + pq * NTH;
      if (k <= M/2) {
        int rk  = rev13(k);
        int rmk = rev13((M - k) & (M - 1));
        float2 Zk = L[swz(rk)], Zmk = L[swz(rmk)];
        float2 Ze = make_float2(0.5f*(Zk.x + Zmk.x), 0.5f*(Zk.y - Zmk.y));
        float2 t  = make_float2(Zk.x - Zmk.x, Zk.y + Zmk.y);
        float2 Zo = make_float2(0.5f*t.y, -0.5f*t.x);
        float s, c; __sincosf(-PI_F * (float)k * (1.0f/(float)M), &s, &c);
        float2 W = make_float2(c, s);
        float2 WZo = cmul(W, Zo);
        Kk[pq]  = cadd(Ze, WZo);
        Kmk[pq] = conjf2(csub(Ze, WZo));
      }
    }
    __syncthreads();
  }

  // ---------------- Phase B: signal FFT ----------------
  {
    const float* xp = x + (size_t)b * (8192 * 1024) + d;
    float2 p[32];
#pragma unroll
    for (int t = 0; t < 16; ++t) {
      int m = tid + t * NTH;
      p[t] = make_float2(xp[(size_t)(2*m)     * 1024],
                         xp[(size_t)(2*m + 1) * 1024]);
    }
#pragma unroll
    for (int t = 16; t < 32; ++t) p[t] = make_float2(0.f, 0.f);
    fft5_regs<256, false, true, false>(p, tid);      // halves 4096..256
#pragma unroll
    for (int t = 0; t < 32; ++t) L[swz(tid + t * 256)] = p[t];
  }
  __syncthreads();
  pass5_lds<8, false>(L, tid);                       // halves 128..8
  __syncthreads();
  pass3_lds<false>(L, tid);                          // halves 4,2,1
  __syncthreads();

  // ---------------- Phase C: unpack * K, repack (in place, pairwise) -------
  {
    // Gather K first (short-lived; L3-resident workspace), then compute.
    float4 kv[MAXP];
    if (kf != nullptr) {
      const float4* kfp = kf + (size_t)d * (M/2 + 1);
#pragma unroll
      for (int pq = 0; pq < MAXP; ++pq) {
        int k = tid + pq * NTH;
        if (k <= M/2) kv[pq] = kfp[k];
      }
    } else {
#pragma unroll
      for (int pq = 0; pq < MAXP; ++pq)
        kv[pq] = make_float4(Kk[pq].x, Kk[pq].y, Kmk[pq].x, Kmk[pq].y);
    }
#pragma unroll
    for (int pq = 0; pq < MAXP; ++pq) {
      int k = tid + pq * NTH;
      if (k <= M/2) {
        int rk  = rev13(k);
        int rmk = rev13((M - k) & (M - 1));
        float2 Zk = L[swz(rk)], Zmk = L[swz(rmk)];
        float2 Ze = make_float2(0.5f*(Zk.x + Zmk.x), 0.5f*(Zk.y - Zmk.y));
        float2 t  = make_float2(Zk.x - Zmk.x, Zk.y + Zmk.y);
        float2 Zo = make_float2(0.5f*t.y, -0.5f*t.x);
        float s, c; __sincosf(-PI_F * (float)k * (1.0f/(float)M), &s, &c);
        float2 W = make_float2(c, s);
        float2 WZo = cmul(W, Zo);
        float2 Uk  = cadd(Ze, WZo);
        float2 Umk = conjf2(csub(Ze, WZo));
        float2 Yk  = cmul(Uk,  make_float2(kv[pq].x, kv[pq].y));
        float2 Ymk = cmul(Umk, make_float2(kv[pq].z, kv[pq].w));
        float2 Ye  = make_float2(0.5f*(Yk.x + Ymk.x), 0.5f*(Yk.y - Ymk.y));
        float2 t2  = make_float2(0.5f*(Yk.x - Ymk.x), 0.5f*(Yk.y + Ymk.y));
        float2 Zoy = cmul(conjf2(W), t2);
        float2 Zyk  = make_float2(Ye.x - Zoy.y, Ye.y + Zoy.x);
        float2 Zymk = make_float2(Ye.x + Zoy.y, Zoy.x - Ye.y);
        L[swz(rk)]  = Zyk;
        L[swz(rmk)] = Zymk;                  // k==0 / k==M/2: same slot, same value
      }
    }
  }
  __syncthreads();

  // ---------------- Phase D: inverse FFT ----------------
  pass3_lds<true>(L, tid);                   // halves 1,2,4
  __syncthreads();
  pass5_lds<8, true>(L, tid);                // halves 8..128
  __syncthreads();

  // Final inverse pass (halves 256..4096) + direct register store of y.
  {
    float2 p[32];
#pragma unroll
    for (int t = 0; t < 32; ++t) p[t] = L[swz(tid + t * 256)];
    fft5_regs<256, true, false, true>(p, tid);
    float* yp = y + (size_t)b * (8192 * 1024) + d;
    const float inv = 1.0f / (float)M;
#pragma unroll
    for (int t = 0; t < 16; ++t) {
      int m = tid + t * NTH;                 // first l samples (packed pairs)
      yp[(size_t)(2*m)     * 1024] = p[t].x * inv;
      yp[(size_t)(2*m + 1) * 1024] = p[t].y * inv;
    }
  }
}

extern "C" void kernel_launch(void* const* d_in, const int* in_sizes, int n_in,
                              void* d_out, int out_size, void* d_ws, size_t ws_size,
                              hipStream_t stream) {
  const float* x    = (const float*)d_in[0];   // (b, l, d) fp32
  const float* filt = (const float*)d_in[1];   // (d, l) fp32
  float* y = (float*)d_out;                    // (b, l, d) fp32

  const int D = 1024, Lseq = 8192;
  const int B = in_sizes[0] / (D * Lseq);      // 4

  const size_t kf_bytes = (size_t)D * (M/2 + 1) * sizeof(float4);  // ~67 MB
  const float4* kf = nullptr;
  if (d_ws != nullptr && ws_size >= kf_bytes) {
    hipLaunchKernelGGL(filt_fft_kernel, dim3(D), dim3(NTH), 0, stream,
                       filt, (float4*)d_ws);
    kf = (const float4*)d_ws;
  }

  dim3 grid(B * D), block(NTH);
  hipLaunchKernelGGL(longconv_fft_kernel, grid, block, 0, stream, x, filt, kf, y, B);
}

// Round 4
// 620.628 us; speedup vs baseline: 2.4992x; 1.3544x over previous
//
#include <hip/hip_runtime.h>

// FFT-based causal long convolution for (b=4, l=8192, d=1024) fp32.
// One workgroup per (b, d) pair. Real FFT of N=16384 as complex FFT of M=8192
// via even/odd packing; 64 KB LDS holds the whole sequence.
//
// vs round 3 (spill regression):
//  - Phase C restored to the round-1-proven pattern: kf[k] loaded INSIDE each
//    unrolled iteration (short-lived float4), never gathered into a kv[17]
//    array. The manual gather put 68 VGPRs live across the whole phase on top
//    of the fft5 pressure -> scratch spills -> ~5 MB/XCD spill working set
//    thrashed L2 -> y-line merging collapsed (WRITE 726 MB vs ideal 128).
//  - Fallback path (kf==nullptr, persistent Kk/Kmk registers) moved to a
//    SEPARATE kernel so the hot kernel carries no K arrays / scratch slots.
//  - Unchanged: radix-2^5/2^5/2^3 fused passes (3 LDS round-trips per FFT),
//    global<->register first/last passes, per-d filter spectrum precompute,
//    bijective XCD swizzle (each XCD: one b, 512 consecutive d).

#define M 8192
#define NTH 256
#define MAXP 17           // ceil((M/2+1)/NTH)

__device__ __forceinline__ float2 cadd(float2 a, float2 b){ return make_float2(a.x+b.x, a.y+b.y); }
__device__ __forceinline__ float2 csub(float2 a, float2 b){ return make_float2(a.x-b.x, a.y-b.y); }
__device__ __forceinline__ float2 cmul(float2 a, float2 b){ return make_float2(a.x*b.x - a.y*b.y, a.x*b.y + a.y*b.x); }
__device__ __forceinline__ float2 conjf2(float2 a){ return make_float2(a.x, -a.y); }
__device__ __forceinline__ int rev13(int k){ return (int)(__brev((unsigned)k) >> 19); }
__device__ __forceinline__ int swz(int e){ return e ^ ((e >> 4) & 15) ^ ((e >> 8) & 15); }

static __device__ const float PI_F = 3.14159265358979323846f;

// cos/sin(pi*u/16); indexed with compile-time u in fully unrolled loops.
constexpr float CR_C[17] = {
  1.f, 0.98078528f, 0.92387953f, 0.83146961f, 0.70710678f,
  0.55557023f, 0.38268343f, 0.19509032f, 0.f, -0.19509032f,
  -0.38268343f, -0.55557023f, -0.70710678f, -0.83146961f,
  -0.92387953f, -0.98078528f, -1.f };
constexpr float CR_S[17] = {
  0.f, 0.19509032f, 0.38268343f, 0.55557023f, 0.70710678f,
  0.83146961f, 0.92387953f, 0.98078528f, 1.f, 0.98078528f,
  0.92387953f, 0.83146961f, 0.70710678f, 0.55557023f,
  0.38268343f, 0.19509032f, 0.f };

// a * e^{-i*pi*idx/16} (fwd) or a * e^{+i*pi*idx/16} (inv); idx compile-time.
__device__ __forceinline__ float2 cmul_cr(float2 a, int idx, bool inv) {
  if (idx == 0) return a;
  const float c = CR_C[idx], s = CR_S[idx];
  if (!inv) return make_float2(a.x*c + a.y*s, a.y*c - a.x*s);
  return make_float2(a.x*c - a.y*s, a.x*s + a.y*c);
}

// 5 fused radix-2 stages on a 32-point register group.
// Group = global indices { base + t*HS : t=0..31 }, r = base mod HS.
// Forward (DIF): halves 16HS..HS. Inverse (DIT): halves HS..16HS.
// FIRST_PAD: forward only, p[16..31] known zero (zero-padded input).
// LAST_HALF: inverse only, final-stage upper outputs not needed.
template<int HS, bool INV, bool FIRST_PAD, bool LAST_HALF>
__device__ __forceinline__ void fft5_regs(float2 (&p)[32], int r) {
  float s, c;
  const float th = PI_F * (float)r * (1.0f / (16.0f * (float)HS));
  __sincosf(INV ? th : -th, &s, &c);
  float2 w[5];
  w[0] = make_float2(c, s);
  w[1] = cmul(w[0], w[0]);
  w[2] = cmul(w[1], w[1]);
  w[3] = cmul(w[2], w[2]);
  w[4] = cmul(w[3], w[3]);
  if (!INV) {
#pragma unroll
    for (int st = 0; st < 5; ++st) {
      const int D = 16 >> st;
#pragma unroll
      for (int t0 = 0; t0 < 32; ++t0) {
        if ((t0 & D) == 0) {
          const int u = t0 & (D - 1);
          float2 a = p[t0];
          if (FIRST_PAD && st == 0) {
            // b == 0: sum = a, diff = a.
            p[t0 + D] = cmul_cr(cmul(a, w[0]), u, false);
          } else {
            float2 b = p[t0 + D];
            p[t0] = cadd(a, b);
            p[t0 + D] = cmul_cr(cmul(csub(a, b), w[st]), u * (16 / D), false);
          }
        }
      }
    }
  } else {
#pragma unroll
    for (int st = 0; st < 5; ++st) {
      const int D = 1 << st;
#pragma unroll
      for (int t0 = 0; t0 < 32; ++t0) {
        if ((t0 & D) == 0) {
          const int u = t0 & (D - 1);
          float2 b = cmul_cr(cmul(p[t0 + D], w[4 - st]), u * (16 / D), true);
          float2 a = p[t0];
          p[t0] = cadd(a, b);
          if (!(LAST_HALF && st == 4)) p[t0 + D] = csub(a, b);
        }
      }
    }
  }
}

// Middle fused-5 pass, LDS -> registers -> LDS.
template<int HS, bool INV>
__device__ __forceinline__ void pass5_lds(float2* L, int tid) {
  const int r = tid & (HS - 1);
  const int base = ((tid - r) << 5) + r;     // (tid/HS)*32*HS + r
  float2 p[32];
#pragma unroll
  for (int t = 0; t < 32; ++t) p[t] = L[swz(base + t * HS)];
  fft5_regs<HS, INV, false, false>(p, r);
#pragma unroll
  for (int t = 0; t < 32; ++t) L[swz(base + t * HS)] = p[t];
}

// 3 fused stages (halves 4,2,1), hs=1: 4 groups of 8 consecutive points per
// thread, r=0 => no sincos, constant roots only.
template<bool INV>
__device__ __forceinline__ void pass3_lds(float2* L, int tid) {
#pragma unroll
  for (int g = 0; g < 4; ++g) {
    const int base = tid * 32 + g * 8;
    float2 p[8];
#pragma unroll
    for (int t = 0; t < 8; ++t) p[t] = L[swz(base + t)];
    if (!INV) {
#pragma unroll
      for (int st = 0; st < 3; ++st) {
        const int D = 4 >> st;
#pragma unroll
        for (int t0 = 0; t0 < 8; ++t0) {
          if ((t0 & D) == 0) {
            const int u = t0 & (D - 1);
            float2 a = p[t0], b = p[t0 + D];
            p[t0] = cadd(a, b);
            p[t0 + D] = cmul_cr(csub(a, b), u * (16 / D), false);
          }
        }
      }
    } else {
#pragma unroll
      for (int st = 0; st < 3; ++st) {
        const int D = 1 << st;
#pragma unroll
        for (int t0 = 0; t0 < 8; ++t0) {
          if ((t0 & D) == 0) {
            const int u = t0 & (D - 1);
            float2 b = cmul_cr(p[t0 + D], u * (16 / D), true);
            float2 a = p[t0];
            p[t0] = cadd(a, b);
            p[t0 + D] = csub(a, b);
          }
        }
      }
    }
#pragma unroll
    for (int t = 0; t < 8; ++t) L[swz(base + t)] = p[t];
  }
}

// Precompute per-d filter spectrum: (K[k], K[M-k]) for k=0..M/2 as float4.
__global__ __launch_bounds__(NTH, 2)
void filt_fft_kernel(const float* __restrict__ filt, float4* __restrict__ kf) {
  __shared__ float2 L[M];
  const int tid = threadIdx.x;
  const int d = blockIdx.x;
  const float* fp = filt + (size_t)d * 8192;
  {
    float2 p[32];
#pragma unroll
    for (int t = 0; t < 16; ++t) {
      int m = tid + t * NTH;
      p[t] = make_float2(fp[2*m], fp[2*m + 1]);
    }
#pragma unroll
    for (int t = 16; t < 32; ++t) p[t] = make_float2(0.f, 0.f);
    fft5_regs<256, false, true, false>(p, tid);      // halves 4096..256
#pragma unroll
    for (int t = 0; t < 32; ++t) L[swz(tid + t * 256)] = p[t];
  }
  __syncthreads();
  pass5_lds<8, false>(L, tid);                       // halves 128..8
  __syncthreads();
  pass3_lds<false>(L, tid);                          // halves 4,2,1
  __syncthreads();
  float4* out = kf + (size_t)d * (M/2 + 1);
  for (int k = tid; k <= M/2; k += NTH) {
    int rk  = rev13(k);
    int rmk = rev13((M - k) & (M - 1));
    float2 Zk = L[swz(rk)], Zmk = L[swz(rmk)];
    float2 Ze = make_float2(0.5f*(Zk.x + Zmk.x), 0.5f*(Zk.y - Zmk.y));
    float2 t  = make_float2(Zk.x - Zmk.x, Zk.y + Zmk.y);
    float2 Zo = make_float2(0.5f*t.y, -0.5f*t.x);
    float s, c; __sincosf(-PI_F * (float)k * (1.0f/(float)M), &s, &c);
    float2 W = make_float2(c, s);
    float2 WZo = cmul(W, Zo);
    float2 Kk = cadd(Ze, WZo);
    float2 Km = conjf2(csub(Ze, WZo));
    out[k] = make_float4(Kk.x, Kk.y, Km.x, Km.y);
  }
}

// ---------------- HOT KERNEL: requires kf (no fallback arrays) -------------
__global__ __launch_bounds__(NTH, 2)
void longconv_kf_kernel(const float* __restrict__ x,
                        const float4* __restrict__ kf,
                        float* __restrict__ y) {
  __shared__ float2 L[M];                    // 64 KB
  const int tid = threadIdx.x;

  // Bijective XCD swizzle: XCD j owns 512 consecutive blk = one b, 512
  // consecutive d -> co-resident blocks share x/y cache lines in its L2.
  const int nwg = gridDim.x;                 // 4096, multiple of 8
  const int cpx = nwg >> 3;
  const int bid = blockIdx.x;
  const int blk = (bid & 7) * cpx + (bid >> 3);
  const int d = blk & 1023;
  const int b = blk >> 10;

  // ---------------- Phase B: signal FFT ----------------
  {
    const float* xp = x + (size_t)b * (8192 * 1024) + d;
    float2 p[32];
#pragma unroll
    for (int t = 0; t < 16; ++t) {
      int m = tid + t * NTH;
      p[t] = make_float2(xp[(size_t)(2*m)     * 1024],
                         xp[(size_t)(2*m + 1) * 1024]);
    }
#pragma unroll
    for (int t = 16; t < 32; ++t) p[t] = make_float2(0.f, 0.f);
    fft5_regs<256, false, true, false>(p, tid);      // halves 4096..256
#pragma unroll
    for (int t = 0; t < 32; ++t) L[swz(tid + t * 256)] = p[t];
  }
  __syncthreads();
  pass5_lds<8, false>(L, tid);                       // halves 128..8
  __syncthreads();
  pass3_lds<false>(L, tid);                          // halves 4,2,1
  __syncthreads();

  // ------- Phase C: unpack * K, repack (round-1 pattern: load in-loop) -----
  {
    const float4* kfp = kf + (size_t)d * (M/2 + 1);
#pragma unroll
    for (int pq = 0; pq < MAXP; ++pq) {
      int k = tid + pq * NTH;
      if (k <= M/2) {
        float4 kv = kfp[k];                  // short-lived, per-iteration
        int rk  = rev13(k);
        int rmk = rev13((M - k) & (M - 1));
        float2 Zk = L[swz(rk)], Zmk = L[swz(rmk)];
        float2 Ze = make_float2(0.5f*(Zk.x + Zmk.x), 0.5f*(Zk.y - Zmk.y));
        float2 t  = make_float2(Zk.x - Zmk.x, Zk.y + Zmk.y);
        float2 Zo = make_float2(0.5f*t.y, -0.5f*t.x);
        float s, c; __sincosf(-PI_F * (float)k * (1.0f/(float)M), &s, &c);
        float2 W = make_float2(c, s);
        float2 WZo = cmul(W, Zo);
        float2 Uk  = cadd(Ze, WZo);
        float2 Umk = conjf2(csub(Ze, WZo));
        float2 Yk  = cmul(Uk,  make_float2(kv.x, kv.y));
        float2 Ymk = cmul(Umk, make_float2(kv.z, kv.w));
        float2 Ye  = make_float2(0.5f*(Yk.x + Ymk.x), 0.5f*(Yk.y - Ymk.y));
        float2 t2  = make_float2(0.5f*(Yk.x - Ymk.x), 0.5f*(Yk.y + Ymk.y));
        float2 Zoy = cmul(conjf2(W), t2);
        float2 Zyk  = make_float2(Ye.x - Zoy.y, Ye.y + Zoy.x);
        float2 Zymk = make_float2(Ye.x + Zoy.y, Zoy.x - Ye.y);
        L[swz(rk)]  = Zyk;
        L[swz(rmk)] = Zymk;                  // k==0 / k==M/2: same slot, same value
      }
    }
  }
  __syncthreads();

  // ---------------- Phase D: inverse FFT ----------------
  pass3_lds<true>(L, tid);                   // halves 1,2,4
  __syncthreads();
  pass5_lds<8, true>(L, tid);                // halves 8..128
  __syncthreads();

  // Final inverse pass (halves 256..4096) + direct register store of y.
  {
    float2 p[32];
#pragma unroll
    for (int t = 0; t < 32; ++t) p[t] = L[swz(tid + t * 256)];
    fft5_regs<256, true, false, true>(p, tid);
    float* yp = y + (size_t)b * (8192 * 1024) + d;
    const float inv = 1.0f / (float)M;
#pragma unroll
    for (int t = 0; t < 16; ++t) {
      int m = tid + t * NTH;                 // first l samples (packed pairs)
      yp[(size_t)(2*m)     * 1024] = p[t].x * inv;
      yp[(size_t)(2*m + 1) * 1024] = p[t].y * inv;
    }
  }
}

// ---------------- FALLBACK: no workspace; K in registers (may spill) -------
__global__ __launch_bounds__(NTH, 2)
void longconv_fallback_kernel(const float* __restrict__ x,
                              const float* __restrict__ filt,
                              float* __restrict__ y) {
  __shared__ float2 L[M];
  const int tid = threadIdx.x;
  const int nwg = gridDim.x;
  const int cpx = nwg >> 3;
  const int bid = blockIdx.x;
  const int blk = (bid & 7) * cpx + (bid >> 3);
  const int d = blk & 1023;
  const int b = blk >> 10;

  float2 Kk[MAXP], Kmk[MAXP];

  {
    const float* fp = filt + (size_t)d * 8192;
    float2 p[32];
#pragma unroll
    for (int t = 0; t < 16; ++t) {
      int m = tid + t * NTH;
      p[t] = make_float2(fp[2*m], fp[2*m + 1]);
    }
#pragma unroll
    for (int t = 16; t < 32; ++t) p[t] = make_float2(0.f, 0.f);
    fft5_regs<256, false, true, false>(p, tid);
#pragma unroll
    for (int t = 0; t < 32; ++t) L[swz(tid + t * 256)] = p[t];
  }
  __syncthreads();
  pass5_lds<8, false>(L, tid);
  __syncthreads();
  pass3_lds<false>(L, tid);
  __syncthreads();
#pragma unroll
  for (int pq = 0; pq < MAXP; ++pq) {
    int k = tid + pq * NTH;
    if (k <= M/2) {
      int rk  = rev13(k);
      int rmk = rev13((M - k) & (M - 1));
      float2 Zk = L[swz(rk)], Zmk = L[swz(rmk)];
      float2 Ze = make_float2(0.5f*(Zk.x + Zmk.x), 0.5f*(Zk.y - Zmk.y));
      float2 t  = make_float2(Zk.x - Zmk.x, Zk.y + Zmk.y);
      float2 Zo = make_float2(0.5f*t.y, -0.5f*t.x);
      float s, c; __sincosf(-PI_F * (float)k * (1.0f/(float)M), &s, &c);
      float2 W = make_float2(c, s);
      float2 WZo = cmul(W, Zo);
      Kk[pq]  = cadd(Ze, WZo);
      Kmk[pq] = conjf2(csub(Ze, WZo));
    }
  }
  __syncthreads();

  {
    const float* xp = x + (size_t)b * (8192 * 1024) + d;
    float2 p[32];
#pragma unroll
    for (int t = 0; t < 16; ++t) {
      int m = tid + t * NTH;
      p[t] = make_float2(xp[(size_t)(2*m)     * 1024],
                         xp[(size_t)(2*m + 1) * 1024]);
    }
#pragma unroll
    for (int t = 16; t < 32; ++t) p[t] = make_float2(0.f, 0.f);
    fft5_regs<256, false, true, false>(p, tid);
#pragma unroll
    for (int t = 0; t < 32; ++t) L[swz(tid + t * 256)] = p[t];
  }
  __syncthreads();
  pass5_lds<8, false>(L, tid);
  __syncthreads();
  pass3_lds<false>(L, tid);
  __syncthreads();

#pragma unroll
  for (int pq = 0; pq < MAXP; ++pq) {
    int k = tid + pq * NTH;
    if (k <= M/2) {
      int rk  = rev13(k);
      int rmk = rev13((M - k) & (M - 1));
      float2 Zk = L[swz(rk)], Zmk = L[swz(rmk)];
      float2 Ze = make_float2(0.5f*(Zk.x + Zmk.x), 0.5f*(Zk.y - Zmk.y));
      float2 t  = make_float2(Zk.x - Zmk.x, Zk.y + Zmk.y);
      float2 Zo = make_float2(0.5f*t.y, -0.5f*t.x);
      float s, c; __sincosf(-PI_F * (float)k * (1.0f/(float)M), &s, &c);
      float2 W = make_float2(c, s);
      float2 WZo = cmul(W, Zo);
      float2 Uk  = cadd(Ze, WZo);
      float2 Umk = conjf2(csub(Ze, WZo));
      float2 Yk  = cmul(Uk,  Kk[pq]);
      float2 Ymk = cmul(Umk, Kmk[pq]);
      float2 Ye  = make_float2(0.5f*(Yk.x + Ymk.x), 0.5f*(Yk.y - Ymk.y));
      float2 t2  = make_float2(0.5f*(Yk.x - Ymk.x), 0.5f*(Yk.y + Ymk.y));
      float2 Zoy = cmul(conjf2(W), t2);
      float2 Zyk  = make_float2(Ye.x - Zoy.y, Ye.y + Zoy.x);
      float2 Zymk = make_float2(Ye.x + Zoy.y, Zoy.x - Ye.y);
      L[swz(rk)]  = Zyk;
      L[swz(rmk)] = Zymk;
    }
  }
  __syncthreads();

  pass3_lds<true>(L, tid);
  __syncthreads();
  pass5_lds<8, true>(L, tid);
  __syncthreads();

  {
    float2 p[32];
#pragma unroll
    for (int t = 0; t < 32; ++t) p[t] = L[swz(tid + t * 256)];
    fft5_regs<256, true, false, true>(p, tid);
    float* yp = y + (size_t)b * (8192 * 1024) + d;
    const float inv = 1.0f / (float)M;
#pragma unroll
    for (int t = 0; t < 16; ++t) {
      int m = tid + t * NTH;
      yp[(size_t)(2*m)     * 1024] = p[t].x * inv;
      yp[(size_t)(2*m + 1) * 1024] = p[t].y * inv;
    }
  }
}

extern "C" void kernel_launch(void* const* d_in, const int* in_sizes, int n_in,
                              void* d_out, int out_size, void* d_ws, size_t ws_size,
                              hipStream_t stream) {
  const float* x    = (const float*)d_in[0];   // (b, l, d) fp32
  const float* filt = (const float*)d_in[1];   // (d, l) fp32
  float* y = (float*)d_out;                    // (b, l, d) fp32

  const int D = 1024, Lseq = 8192;
  const int B = in_sizes[0] / (D * Lseq);      // 4

  const size_t kf_bytes = (size_t)D * (M/2 + 1) * sizeof(float4);  // ~67 MB
  dim3 grid(B * D), block(NTH);

  if (d_ws != nullptr && ws_size >= kf_bytes) {
    hipLaunchKernelGGL(filt_fft_kernel, dim3(D), dim3(NTH), 0, stream,
                       filt, (float4*)d_ws);
    hipLaunchKernelGGL(longconv_kf_kernel, grid, block, 0, stream,
                       x, (const float4*)d_ws, y);
  } else {
    hipLaunchKernelGGL(longconv_fallback_kernel, grid, block, 0, stream,
                       x, filt, y);
  }
}